// Round 3
// baseline (549.222 us; speedup 1.0000x reference)
//
#include <hip/hip_runtime.h>
#include <stdint.h>

#define K_DIM 4096
#define N_DIM 4096
#define KB    32          // K / 128
#define QMAXF 127.0f

typedef int v4i __attribute__((ext_vector_type(4)));

__device__ __forceinline__ void async_copy16(void* lds, const void* gptr) {
    __builtin_amdgcn_global_load_lds(
        (__attribute__((address_space(1))) void*)gptr,
        (__attribute__((address_space(3))) void*)lds, 16, 0, 0);
}

// ---------------- activation quant ----------------
// 2 rows per block; 8 independent float4 loads hoisted per thread (MLP fix:
// old version had 4 outstanding loads -> latency-bound at ~1.4 TB/s).
__global__ __launch_bounds__(256) void act_quant_kernel(
    const float* __restrict__ x, int8_t* __restrict__ xq,
    float* __restrict__ xs_t, int M)
{
    const int t   = threadIdx.x;
    const int r   = t >> 7;           // 0..1 (row within block; wave-aligned)
    const int tid = t & 127;          // 128 threads per row
    const int m   = blockIdx.x * 2 + r;
    const float* xrow = x + (size_t)m * K_DIM;
    int8_t* qrow = xq + (size_t)m * K_DIM;

    float4 v[8];
#pragma unroll
    for (int p = 0; p < 8; ++p)
        v[p] = *(const float4*)(xrow + p * 512 + tid * 4);

#pragma unroll
    for (int p = 0; p < 8; ++p) {
        float a = fmaxf(fmaxf(fabsf(v[p].x), fabsf(v[p].y)),
                        fmaxf(fabsf(v[p].z), fabsf(v[p].w)));
#pragma unroll
        for (int off = 1; off < 32; off <<= 1)
            a = fmaxf(a, __shfl_xor(a, off, 64));
        const float s = fmaxf(a / QMAXF, 1e-12f);
        const float inv = 1.0f / s;
        char4 pk;
        pk.x = (char)(int)fminf(fmaxf(rintf(v[p].x * inv), -128.f), 127.f);
        pk.y = (char)(int)fminf(fmaxf(rintf(v[p].y * inv), -128.f), 127.f);
        pk.z = (char)(int)fminf(fmaxf(rintf(v[p].z * inv), -128.f), 127.f);
        pk.w = (char)(int)fminf(fmaxf(rintf(v[p].w * inv), -128.f), 127.f);
        *(char4*)(qrow + p * 512 + tid * 4) = pk;
        if ((tid & 31) == 0) {
            const int g = p * 4 + (tid >> 5);
            xs_t[(size_t)g * M + m] = s;             // transposed [kb][M]
        }
    }
}

// ---------------- weight quant: per 128x128 block ----------------
__global__ __launch_bounds__(256) void weight_quant_kernel(
    const float* __restrict__ w, int8_t* __restrict__ wq, float* __restrict__ ws)
{
    const int nb = blockIdx.x >> 5;
    const int kb = blockIdx.x & 31;
    const int t  = threadIdx.x;
    const int n0 = nb * 128, k0 = kb * 128;

    float4 vals[16];
    float a = 0.f;
#pragma unroll
    for (int ii = 0; ii < 16; ++ii) {
        const int e = ii * 1024 + t * 4;
        const int row = e >> 7, col = e & 127;
        float4 v = *(const float4*)(w + (size_t)(n0 + row) * K_DIM + k0 + col);
        vals[ii] = v;
        a = fmaxf(a, fmaxf(fmaxf(fabsf(v.x), fabsf(v.y)), fmaxf(fabsf(v.z), fabsf(v.w))));
    }
#pragma unroll
    for (int off = 1; off < 64; off <<= 1)
        a = fmaxf(a, __shfl_xor(a, off, 64));
    __shared__ float wred[4];
    if ((t & 63) == 0) wred[t >> 6] = a;
    __syncthreads();
    a = fmaxf(fmaxf(wred[0], wred[1]), fmaxf(wred[2], wred[3]));
    const float s = fmaxf(a / QMAXF, 1e-12f);
    const float inv = 1.0f / s;
    if (t == 0) ws[nb * KB + kb] = s;

#pragma unroll
    for (int ii = 0; ii < 16; ++ii) {
        const int e = ii * 1024 + t * 4;
        const int row = e >> 7, col = e & 127;
        float4 v = vals[ii];
        char4 pk;
        pk.x = (char)(int)fminf(fmaxf(rintf(v.x * inv), -128.f), 127.f);
        pk.y = (char)(int)fminf(fmaxf(rintf(v.y * inv), -128.f), 127.f);
        pk.z = (char)(int)fminf(fmaxf(rintf(v.z * inv), -128.f), 127.f);
        pk.w = (char)(int)fminf(fmaxf(rintf(v.w * inv), -128.f), 127.f);
        *(char4*)(wq + (size_t)(n0 + row) * K_DIM + k0 + col) = pk;
    }
}

// ---------------- int8 GEMM with grouped dequant + bias ----------------
// 256x128 block tile; 4 waves (2x2), each 128x64 via 8x4 of 16x16x64 i8 MFMA.
// Fat wave tiles cut LDS fragment reads from 4 B/output to 3 B/output
// (LDS pipe was co-limiting at 64x64). XOR-swizzled LDS (conflict-free,
// verified R2: SQ_LDS_BANK_CONFLICT=0). Bias folded into acc init; dequant
// uses explicit fmaf (no fast-math -> compiler won't contract mul+add).
__global__ __launch_bounds__(256, 2) void gemm_kernel(
    const int8_t* __restrict__ xq, const int8_t* __restrict__ wq,
    const float* __restrict__ xs_t, const float* __restrict__ ws,
    const float* __restrict__ bias, float* __restrict__ out, int M)
{
    __shared__ __align__(16) int8_t As[256 * 128];   // 32 KB
    __shared__ __align__(16) int8_t Bs[128 * 128];   // 16 KB
    __shared__ __align__(16) float  xs_s[KB * 256];  // 32 KB: [kb][row]
    __shared__ float ws_s[KB];

    const int t    = threadIdx.x;
    const int lane = t & 63;
    const int wave = t >> 6;
    const int nb   = blockIdx.x;
    const int n0   = nb * 128;
    const int m0   = blockIdx.y * 256;

    // stage activation scales: [kb][256 rows] = 8192 floats
#pragma unroll
    for (int i = 0; i < 8; ++i) {
        const int idx = t * 4 + i * 1024;
        const int kbi = idx >> 8, r = idx & 255;
        *(float4*)&xs_s[idx] = *(const float4*)&xs_t[(size_t)kbi * M + m0 + r];
    }
    if (t < KB) ws_s[t] = ws[nb * KB + t];

    const int wm    = (wave >> 1) * 128;   // wave row offset (0/128)
    const int wn    = (wave & 1) * 64;     // wave col offset (0/64)
    const int frow  = lane & 15;
    const int q     = lane >> 4;                 // k-chunk index (0..3)
    const int quad4 = q * 4;                     // C/D row base within 16-tile
    const int sw0   = (q ^ (frow & 7)) * 16;     // swizzled byte offset
    // chunk q+4 -> offset sw0 ^ 64

    float4 facc[8][4];
#pragma unroll
    for (int j = 0; j < 4; ++j) {
        const float b = bias[n0 + wn + j * 16 + frow];
#pragma unroll
        for (int i = 0; i < 8; ++i)
            facc[i][j] = (float4){b, b, b, b};
    }

    for (int kb = 0; kb < KB; ++kb) {
        __syncthreads();
        const int8_t* Ag = xq + (size_t)m0 * K_DIM + kb * 128;
        const int8_t* Bg = wq + (size_t)n0 * K_DIM + kb * 128;
#pragma unroll
        for (int it = 0; it < 8; ++it) {          // A: 256 rows = 2048 chunks
            const int ci  = it * 256 + t;
            const int row = ci >> 3;
            const int c   = (ci & 7) ^ (row & 7);
            async_copy16((void*)&As[(it * 256 + wave * 64) * 16],
                         Ag + (size_t)row * K_DIM + c * 16);
        }
#pragma unroll
        for (int it = 0; it < 4; ++it) {          // B: 128 rows = 1024 chunks
            const int ci  = it * 256 + t;
            const int row = ci >> 3;
            const int c   = (ci & 7) ^ (row & 7);
            async_copy16((void*)&Bs[(it * 256 + wave * 64) * 16],
                         Bg + (size_t)row * K_DIM + c * 16);
        }
        __syncthreads();

        v4i b0[4], b1[4];
#pragma unroll
        for (int j = 0; j < 4; ++j) {
            b0[j] = *(const v4i*)&Bs[(wn + j * 16 + frow) * 128 + sw0];
            b1[j] = *(const v4i*)&Bs[(wn + j * 16 + frow) * 128 + (sw0 ^ 64)];
        }
        const float wskb = ws_s[kb];
#pragma unroll
        for (int i = 0; i < 8; ++i) {
            const v4i a0 = *(const v4i*)&As[(wm + i * 16 + frow) * 128 + sw0];
            const v4i a1 = *(const v4i*)&As[(wm + i * 16 + frow) * 128 + (sw0 ^ 64)];
            float4 xs4 = *(const float4*)&xs_s[kb * 256 + wm + i * 16 + quad4];
            const float s0 = xs4.x * wskb, s1 = xs4.y * wskb;
            const float s2 = xs4.z * wskb, s3 = xs4.w * wskb;
#pragma unroll
            for (int j = 0; j < 4; ++j) {
                v4i d = __builtin_amdgcn_mfma_i32_16x16x64_i8(a0, b0[j], (v4i){0, 0, 0, 0}, 0, 0, 0);
                d = __builtin_amdgcn_mfma_i32_16x16x64_i8(a1, b1[j], d, 0, 0, 0);
                facc[i][j].x = __builtin_fmaf((float)d[0], s0, facc[i][j].x);
                facc[i][j].y = __builtin_fmaf((float)d[1], s1, facc[i][j].y);
                facc[i][j].z = __builtin_fmaf((float)d[2], s2, facc[i][j].z);
                facc[i][j].w = __builtin_fmaf((float)d[3], s3, facc[i][j].w);
            }
        }
    }

    // epilogue: C/D layout col = lane&15, row = (lane>>4)*4 + reg
#pragma unroll
    for (int i = 0; i < 8; ++i) {
#pragma unroll
        for (int r = 0; r < 4; ++r) {
            const int row = m0 + wm + i * 16 + quad4 + r;
            float* orow = out + (size_t)row * N_DIM + n0 + wn + frow;
#pragma unroll
            for (int j = 0; j < 4; ++j)
                orow[j * 16] = ((const float*)&facc[i][j])[r];
        }
    }
}

extern "C" void kernel_launch(void* const* d_in, const int* in_sizes, int n_in,
                              void* d_out, int out_size, void* d_ws, size_t ws_size,
                              hipStream_t stream)
{
    const float* x    = (const float*)d_in[0];
    const float* w    = (const float*)d_in[1];
    const float* bias = (const float*)d_in[2];
    float* out = (float*)d_out;
    const int M = in_sizes[0] / K_DIM;   // 8192

    int8_t* xq  = (int8_t*)d_ws;                                 // M*K
    int8_t* wqp = xq + (size_t)M * K_DIM;                        // N*K
    float*  xst = (float*)(wqp + (size_t)N_DIM * K_DIM);         // KB*M  [kb][M]
    float*  wsp = xst + (size_t)KB * M;                          // (N/128)*KB

    act_quant_kernel<<<M / 2, 256, 0, stream>>>(x, xq, xst, M);
    weight_quant_kernel<<<(N_DIM / 128) * KB, 256, 0, stream>>>(w, wqp, wsp);
    gemm_kernel<<<dim3(N_DIM / 128, M / 256), 256, 0, stream>>>(
        xq, wqp, xst, wsp, bias, out, M);
}